// Round 1
// baseline (810.928 us; speedup 1.0000x reference)
//
#include <hip/hip_runtime.h>
#include <hip/hip_bf16.h>
#include <stdint.h>

// ---------------- problem constants ----------------
#define T_TOK 8192      // B*S
#define DIN   1024
#define DOUT  1024
#define HID   2048
#define NEXP  8
#define MAXN  8192      // worst-case tokens per expert

typedef __attribute__((ext_vector_type(8))) short short8;   // 8 bf16 (4 VGPRs)
typedef __attribute__((ext_vector_type(4))) float floatx4;  // MFMA accumulator

__device__ __forceinline__ ushort f2bf(float f) {
    uint32_t u = __float_as_uint(f);
    uint32_t r = (u + 0x7fffu + ((u >> 16) & 1u)) >> 16;   // RNE
    return (ushort)r;
}

// ---------------- fp32 -> bf16 plain convert (for x) ----------------
__global__ void convert_x_kernel(const float* __restrict__ in, ushort* __restrict__ out, int n4) {
    int i = blockIdx.x * blockDim.x + threadIdx.x;
    if (i >= n4) return;
    float4 v = ((const float4*)in)[i];
    ushort4 o;
    o.x = f2bf(v.x); o.y = f2bf(v.y); o.z = f2bf(v.z); o.w = f2bf(v.w);
    ((ushort4*)out)[i] = o;
}

// ---------------- fp32 [R,C] -> bf16 [C,R] tiled transpose ----------------
__global__ void transpose_bf16_kernel(const float* __restrict__ in, ushort* __restrict__ out,
                                      int R, int C) {
    __shared__ float tile[64][65];
    size_t base = (size_t)blockIdx.z * R * C;
    in  += base;
    out += base;
    int r0 = blockIdx.y * 64, c0 = blockIdx.x * 64;
    int t  = threadIdx.x;
    int rr = t >> 4;            // 0..15
    int cc = (t & 15) * 4;      // 0..60
    for (int p = 0; p < 4; p++) {
        int row = rr + p * 16;
        float4 v = *(const float4*)(in + (size_t)(r0 + row) * C + c0 + cc);
        tile[row][cc + 0] = v.x; tile[row][cc + 1] = v.y;
        tile[row][cc + 2] = v.z; tile[row][cc + 3] = v.w;
    }
    __syncthreads();
    for (int p = 0; p < 4; p++) {
        int orow = rr + p * 16;   // output row = original col index
        ushort4 o;
        o.x = f2bf(tile[cc + 0][orow]);
        o.y = f2bf(tile[cc + 1][orow]);
        o.z = f2bf(tile[cc + 2][orow]);
        o.w = f2bf(tile[cc + 3][orow]);
        *(ushort4*)(out + (size_t)(c0 + orow) * R + r0 + cc) = o;
    }
}

// ---------------- gate: logits -> softmax -> top2 -> routing lists ----------------
__global__ void gate_kernel(const float* __restrict__ x, const float* __restrict__ gw,
                            const float* __restrict__ gb, float* __restrict__ ew_out,
                            int* __restrict__ counts, int* __restrict__ expert_tok,
                            float* __restrict__ expert_w) {
    int gid  = blockIdx.x * blockDim.x + threadIdx.x;
    int t    = gid >> 6;
    int lane = threadIdx.x & 63;
    if (t >= T_TOK) return;
    float acc[8];
    #pragma unroll
    for (int e = 0; e < 8; e++) acc[e] = 0.f;
    const float* xrow = x + (size_t)t * DIN;
    #pragma unroll
    for (int i = 0; i < 16; i++) {
        int d = lane + i * 64;
        float xv = xrow[d];
        const float4* wr = (const float4*)(gw + (size_t)d * 8);
        float4 w0 = wr[0], w1 = wr[1];
        acc[0] += xv * w0.x; acc[1] += xv * w0.y; acc[2] += xv * w0.z; acc[3] += xv * w0.w;
        acc[4] += xv * w1.x; acc[5] += xv * w1.y; acc[6] += xv * w1.z; acc[7] += xv * w1.w;
    }
    #pragma unroll
    for (int e = 0; e < 8; e++)
        #pragma unroll
        for (int off = 32; off; off >>= 1) acc[e] += __shfl_xor(acc[e], off);
    if (lane == 0) {
        float l[8], mx = -1e30f;
        #pragma unroll
        for (int e = 0; e < 8; e++) { l[e] = acc[e] + gb[e]; mx = fmaxf(mx, l[e]); }
        float s = 0.f;
        #pragma unroll
        for (int e = 0; e < 8; e++) { l[e] = expf(l[e] - mx); s += l[e]; }
        float inv = 1.f / s;
        #pragma unroll
        for (int e = 0; e < 8; e++) { l[e] *= inv; ew_out[(size_t)t * 8 + e] = l[e]; }
        // top-2 (earliest index wins ties, matching lax.top_k)
        int i1 = 0;
        #pragma unroll
        for (int e = 1; e < 8; e++) if (l[e] > l[i1]) i1 = e;
        int i2 = (i1 == 0) ? 1 : 0;
        #pragma unroll
        for (int e = 0; e < 8; e++) if (e != i1 && l[e] > l[i2]) i2 = e;
        float s2 = l[i1] + l[i2];
        float w1v = l[i1] / s2, w2v = l[i2] / s2;
        int r1 = atomicAdd(&counts[i1], 1);
        expert_tok[i1 * MAXN + r1] = t;
        expert_w [i1 * MAXN + r1] = w1v;
        int r2 = atomicAdd(&counts[i2], 1);
        expert_tok[i2 * MAXN + r2] = t;
        expert_w [i2 * MAXN + r2] = w2v;
    }
}

__global__ void prefix_kernel(const int* __restrict__ counts, int* __restrict__ offsets) {
    if (threadIdx.x == 0 && blockIdx.x == 0) {
        int o = 0;
        for (int e = 0; e < NEXP; e++) { offsets[e] = o; o += counts[e]; }
    }
}

// ---------------- templated 128x128 bf16 MFMA GEMM ----------------
// MODE 0: routed GEMM1  (A = gathered x rows, relu, store bf16 h_buf)
// MODE 1: shared GEMM1  (A = x rows,          relu, store bf16 sh_buf)
// MODE 2: routed GEMM2  (A = h_buf rows, (acc+b)*w, atomicAdd -> Out[token])
// MODE 3: shared GEMM2  (A = sh_buf rows, acc+b,    atomicAdd -> Out[row])
template <int MODE>
__global__ __launch_bounds__(256)
void gemm_kernel(const ushort* __restrict__ A, const ushort* __restrict__ Bt,
                 const float* __restrict__ bias, ushort* __restrict__ Hout,
                 float* __restrict__ Out,
                 const int* __restrict__ counts, const int* __restrict__ offsets,
                 const int* __restrict__ expert_tok, const float* __restrict__ expert_w,
                 int K) {
    const int e = blockIdx.z;
    int cnt, rowbase = 0;
    size_t bt_off = 0;
    const float* bcol = bias;
    if constexpr (MODE == 0) {
        cnt = counts[e]; rowbase = offsets[e];
        bt_off = (size_t)e * HID * DIN; bcol = bias + (size_t)e * HID;
    } else if constexpr (MODE == 1) {
        cnt = T_TOK;
    } else if constexpr (MODE == 2) {
        cnt = counts[e]; rowbase = offsets[e];
        bt_off = (size_t)e * DOUT * HID; bcol = bias + (size_t)e * DOUT;
    } else {
        cnt = T_TOK;
    }

    const int m0 = blockIdx.y * 128;
    if (m0 >= cnt) return;
    const int n0 = blockIdx.x * 128;

    __shared__ ushort As[128][72];   // +8 bf16 pad -> 2-way bank aliasing (free)
    __shared__ ushort Bs[128][72];
    __shared__ int    rowA[128];
    __shared__ int    rowTok[128];
    __shared__ float  rowW[128];

    const int tid = threadIdx.x;
    if (tid < 128) {
        int g = m0 + tid;
        if constexpr (MODE == 0) {
            rowA[tid] = (g < cnt) ? expert_tok[e * MAXN + g] : 0;
        } else if constexpr (MODE == 1) {
            rowA[tid] = g;
        } else if constexpr (MODE == 2) {
            rowA[tid]   = (g < cnt) ? (rowbase + g) : rowbase;
            rowTok[tid] = (g < cnt) ? expert_tok[e * MAXN + g] : 0;
            rowW[tid]   = (g < cnt) ? expert_w[e * MAXN + g] : 0.f;
        } else {
            rowA[tid] = g;
        }
    }
    __syncthreads();

    floatx4 acc[4][4];
    #pragma unroll
    for (int i = 0; i < 4; i++)
        #pragma unroll
        for (int j = 0; j < 4; j++) acc[i][j] = (floatx4){0.f, 0.f, 0.f, 0.f};

    const int wave = tid >> 6, lane = tid & 63;
    const int wm = (wave >> 1) * 64, wn = (wave & 1) * 64;
    const int lm = lane & 15, lq = lane >> 4;
    const int arow_s = tid >> 3;        // 0..31
    const int achunk = (tid & 7) * 8;   // elem offset within 64-wide k-slab

    for (int k0 = 0; k0 < K; k0 += 64) {
        #pragma unroll
        for (int i = 0; i < 4; i++) {
            int r = arow_s + i * 32;
            const ushort* srca = A + (size_t)rowA[r] * K + k0 + achunk;
            *(uint4*)(&As[r][achunk]) = *(const uint4*)srca;
            const ushort* srcb = Bt + bt_off + (size_t)(n0 + r) * K + k0 + achunk;
            *(uint4*)(&Bs[r][achunk]) = *(const uint4*)srcb;
        }
        __syncthreads();
        #pragma unroll
        for (int kk = 0; kk < 64; kk += 32) {
            short8 afr[4], bfr[4];
            #pragma unroll
            for (int mt = 0; mt < 4; mt++)
                afr[mt] = *(const short8*)(&As[wm + mt * 16 + lm][kk + lq * 8]);
            #pragma unroll
            for (int nt = 0; nt < 4; nt++)
                bfr[nt] = *(const short8*)(&Bs[wn + nt * 16 + lm][kk + lq * 8]);
            #pragma unroll
            for (int mt = 0; mt < 4; mt++)
                #pragma unroll
                for (int nt = 0; nt < 4; nt++)
                    acc[mt][nt] = __builtin_amdgcn_mfma_f32_16x16x32_bf16(
                        afr[mt], bfr[nt], acc[mt][nt], 0, 0, 0);
        }
        __syncthreads();
    }

    // epilogue: D[row = lq*4 + r][col = lane&15]
    #pragma unroll
    for (int mt = 0; mt < 4; mt++) {
        int rl_base = wm + mt * 16 + lq * 4;
        #pragma unroll
        for (int nt = 0; nt < 4; nt++) {
            int col = n0 + wn + nt * 16 + lm;
            float bv = bcol[col];
            #pragma unroll
            for (int r = 0; r < 4; r++) {
                int rl = rl_base + r;
                int g  = m0 + rl;
                float v = acc[mt][nt][r];
                if constexpr (MODE == 0) {
                    if (g < cnt) {
                        v = fmaxf(v + bv, 0.f);
                        Hout[(size_t)(rowbase + g) * HID + col] = f2bf(v);
                    }
                } else if constexpr (MODE == 1) {
                    v = fmaxf(v + bv, 0.f);
                    Hout[(size_t)g * HID + col] = f2bf(v);
                } else if constexpr (MODE == 2) {
                    if (g < cnt) {
                        v = (v + bv) * rowW[rl];
                        atomicAdd(&Out[(size_t)rowTok[rl] * DOUT + col], v);
                    }
                } else {
                    atomicAdd(&Out[(size_t)g * DOUT + col], v + bv);
                }
            }
        }
    }
}

// ---------------- launch ----------------
extern "C" void kernel_launch(void* const* d_in, const int* in_sizes, int n_in,
                              void* d_out, int out_size, void* d_ws, size_t ws_size,
                              hipStream_t stream) {
    const float* x   = (const float*)d_in[0];
    const float* gw  = (const float*)d_in[1];
    const float* gb  = (const float*)d_in[2];
    const float* ew1 = (const float*)d_in[3];
    const float* eb1 = (const float*)d_in[4];
    const float* ew2 = (const float*)d_in[5];
    const float* eb2 = (const float*)d_in[6];
    const float* sw1 = (const float*)d_in[7];
    const float* sb1 = (const float*)d_in[8];
    const float* sw2 = (const float*)d_in[9];
    const float* sb2 = (const float*)d_in[10];

    float* out_final = (float*)d_out;
    float* out_ew    = out_final + (size_t)T_TOK * DOUT;

    char* ws = (char*)d_ws;
    size_t off = 0;
    auto alloc = [&](size_t bytes) -> void* {
        void* p = ws + off;
        off += (bytes + 255) & ~(size_t)255;
        return p;
    };
    ushort* x_bf    = (ushort*)alloc((size_t)T_TOK * DIN * 2);
    ushort* ew1t    = (ushort*)alloc((size_t)NEXP * HID * DIN * 2);
    ushort* ew2t    = (ushort*)alloc((size_t)NEXP * DOUT * HID * 2);
    ushort* sw1t    = (ushort*)alloc((size_t)HID * DIN * 2);
    ushort* sw2t    = (ushort*)alloc((size_t)DOUT * HID * 2);
    ushort* h_buf   = (ushort*)alloc((size_t)T_TOK * 2 * HID * 2);   // 16384 slots
    ushort* sh_buf  = (ushort*)alloc((size_t)T_TOK * HID * 2);
    int*    counts  = (int*)alloc(NEXP * 4);
    int*    offsets = (int*)alloc(NEXP * 4);
    int*    etok    = (int*)alloc((size_t)NEXP * MAXN * 4);
    float*  ew      = (float*)alloc((size_t)NEXP * MAXN * 4);

    hipMemsetAsync(d_out, 0, (size_t)T_TOK * DOUT * 4, stream);   // final region only
    hipMemsetAsync(counts, 0, NEXP * 4, stream);

    convert_x_kernel<<<(T_TOK * DIN / 4) / 256, 256, 0, stream>>>(x, x_bf, T_TOK * DIN / 4);
    transpose_bf16_kernel<<<dim3(HID / 64, DIN / 64, NEXP), 256, 0, stream>>>(ew1, ew1t, DIN, HID);
    transpose_bf16_kernel<<<dim3(DOUT / 64, HID / 64, NEXP), 256, 0, stream>>>(ew2, ew2t, HID, DOUT);
    transpose_bf16_kernel<<<dim3(HID / 64, DIN / 64, 1), 256, 0, stream>>>(sw1, sw1t, DIN, HID);
    transpose_bf16_kernel<<<dim3(DOUT / 64, HID / 64, 1), 256, 0, stream>>>(sw2, sw2t, HID, DOUT);

    gate_kernel<<<T_TOK / 4, 256, 0, stream>>>(x, gw, gb, out_ew, counts, etok, ew);
    prefix_kernel<<<1, 64, 0, stream>>>(counts, offsets);

    gemm_kernel<0><<<dim3(HID / 128, MAXN / 128, NEXP), 256, 0, stream>>>(
        x_bf, ew1t, eb1, h_buf, nullptr, counts, offsets, etok, ew, DIN);
    gemm_kernel<1><<<dim3(HID / 128, T_TOK / 128, 1), 256, 0, stream>>>(
        x_bf, sw1t, sb1, sh_buf, nullptr, counts, offsets, etok, ew, DIN);
    gemm_kernel<2><<<dim3(DOUT / 128, MAXN / 128, NEXP), 256, 0, stream>>>(
        h_buf, ew2t, eb2, nullptr, out_final, counts, offsets, etok, ew, HID);
    gemm_kernel<3><<<dim3(DOUT / 128, T_TOK / 128, 1), 256, 0, stream>>>(
        sh_buf, sw2t, sb2, nullptr, out_final, counts, offsets, etok, ew, HID);
}

// Round 2
// 799.959 us; speedup vs baseline: 1.0137x; 1.0137x over previous
//
#include <hip/hip_runtime.h>
#include <hip/hip_bf16.h>
#include <stdint.h>

// ---------------- problem constants ----------------
#define T_TOK 8192      // B*S
#define DIN   1024
#define DOUT  1024
#define HID   2048
#define NEXP  8
#define MAXN  8192      // worst-case tokens per expert

typedef __attribute__((ext_vector_type(8))) short short8;   // 8 bf16 (4 VGPRs)
typedef __attribute__((ext_vector_type(4))) float floatx4;  // MFMA accumulator

__device__ __forceinline__ ushort f2bf(float f) {
    uint32_t u = __float_as_uint(f);
    uint32_t r = (u + 0x7fffu + ((u >> 16) & 1u)) >> 16;   // RNE
    return (ushort)r;
}

// async global->LDS, 16B per lane; LDS dst is wave-uniform base + lane*16
__device__ __forceinline__ void load_lds_16(const ushort* g, ushort* l) {
    __builtin_amdgcn_global_load_lds(
        (const __attribute__((address_space(1))) void*)g,
        (__attribute__((address_space(3))) void*)l, 16, 0, 0);
}

// ---------------- fp32 -> bf16 plain convert (for x) ----------------
__global__ void convert_x_kernel(const float* __restrict__ in, ushort* __restrict__ out, int n4) {
    int i = blockIdx.x * blockDim.x + threadIdx.x;
    if (i >= n4) return;
    float4 v = ((const float4*)in)[i];
    ushort4 o;
    o.x = f2bf(v.x); o.y = f2bf(v.y); o.z = f2bf(v.z); o.w = f2bf(v.w);
    ((ushort4*)out)[i] = o;
}

// ---------------- fp32 [R,C] -> bf16 [C,R] tiled transpose ----------------
__global__ void transpose_bf16_kernel(const float* __restrict__ in, ushort* __restrict__ out,
                                      int R, int C) {
    __shared__ float tile[64][65];
    size_t base = (size_t)blockIdx.z * R * C;
    in  += base;
    out += base;
    int r0 = blockIdx.y * 64, c0 = blockIdx.x * 64;
    int t  = threadIdx.x;
    int rr = t >> 4;            // 0..15
    int cc = (t & 15) * 4;      // 0..60
    for (int p = 0; p < 4; p++) {
        int row = rr + p * 16;
        float4 v = *(const float4*)(in + (size_t)(r0 + row) * C + c0 + cc);
        tile[row][cc + 0] = v.x; tile[row][cc + 1] = v.y;
        tile[row][cc + 2] = v.z; tile[row][cc + 3] = v.w;
    }
    __syncthreads();
    for (int p = 0; p < 4; p++) {
        int orow = rr + p * 16;   // output row = original col index
        ushort4 o;
        o.x = f2bf(tile[cc + 0][orow]);
        o.y = f2bf(tile[cc + 1][orow]);
        o.z = f2bf(tile[cc + 2][orow]);
        o.w = f2bf(tile[cc + 3][orow]);
        *(ushort4*)(out + (size_t)(c0 + orow) * R + r0 + cc) = o;
    }
}

// ---------------- gate: logits -> softmax -> per-token top2 (NO atomics) ----------------
__global__ void gate_compute_kernel(const float* __restrict__ x, const float* __restrict__ gw,
                                    const float* __restrict__ gb, float* __restrict__ ew_out,
                                    int* __restrict__ te1, int* __restrict__ te2,
                                    float* __restrict__ tw1, float* __restrict__ tw2) {
    int gid  = blockIdx.x * blockDim.x + threadIdx.x;
    int t    = gid >> 6;
    int lane = threadIdx.x & 63;
    if (t >= T_TOK) return;
    float acc[8];
    #pragma unroll
    for (int e = 0; e < 8; e++) acc[e] = 0.f;
    const float* xrow = x + (size_t)t * DIN;
    #pragma unroll
    for (int i = 0; i < 16; i++) {
        int d = lane + i * 64;
        float xv = xrow[d];
        const float4* wr = (const float4*)(gw + (size_t)d * 8);
        float4 w0 = wr[0], w1 = wr[1];
        acc[0] += xv * w0.x; acc[1] += xv * w0.y; acc[2] += xv * w0.z; acc[3] += xv * w0.w;
        acc[4] += xv * w1.x; acc[5] += xv * w1.y; acc[6] += xv * w1.z; acc[7] += xv * w1.w;
    }
    #pragma unroll
    for (int e = 0; e < 8; e++)
        #pragma unroll
        for (int off = 32; off; off >>= 1) acc[e] += __shfl_xor(acc[e], off);
    if (lane == 0) {
        float l[8], mx = -1e30f;
        #pragma unroll
        for (int e = 0; e < 8; e++) { l[e] = acc[e] + gb[e]; mx = fmaxf(mx, l[e]); }
        float s = 0.f;
        #pragma unroll
        for (int e = 0; e < 8; e++) { l[e] = expf(l[e] - mx); s += l[e]; }
        float inv = 1.f / s;
        #pragma unroll
        for (int e = 0; e < 8; e++) { l[e] *= inv; ew_out[(size_t)t * 8 + e] = l[e]; }
        // top-2 (earliest index wins ties, matching lax.top_k)
        int i1 = 0;
        #pragma unroll
        for (int e = 1; e < 8; e++) if (l[e] > l[i1]) i1 = e;
        int i2 = (i1 == 0) ? 1 : 0;
        #pragma unroll
        for (int e = 0; e < 8; e++) if (e != i1 && l[e] > l[i2]) i2 = e;
        float s2 = l[i1] + l[i2];
        te1[t] = i1; tw1[t] = l[i1] / s2;
        te2[t] = i2; tw2[t] = l[i2] / s2;
    }
}

// ---------------- build expert lists: LDS histogram, 8 global atomics/block ----------------
__global__ void build_lists_kernel(const int* __restrict__ te1, const int* __restrict__ te2,
                                   const float* __restrict__ tw1, const float* __restrict__ tw2,
                                   int* __restrict__ counts, int* __restrict__ etok,
                                   float* __restrict__ ew) {
    __shared__ int lcnt[NEXP];
    __shared__ int gbase[NEXP];
    int tid = threadIdx.x;
    int t = blockIdx.x * 256 + tid;
    if (tid < NEXP) lcnt[tid] = 0;
    __syncthreads();
    int e1 = te1[t], e2 = te2[t];
    float w1 = tw1[t], w2 = tw2[t];
    int r1 = atomicAdd(&lcnt[e1], 1);   // LDS atomic
    int r2 = atomicAdd(&lcnt[e2], 1);
    __syncthreads();
    if (tid < NEXP) gbase[tid] = atomicAdd(&counts[tid], lcnt[tid]);  // 8 global atomics/block
    __syncthreads();
    int s1 = gbase[e1] + r1;
    etok[e1 * MAXN + s1] = t;
    ew  [e1 * MAXN + s1] = w1;
    int s2 = gbase[e2] + r2;
    etok[e2 * MAXN + s2] = t;
    ew  [e2 * MAXN + s2] = w2;
}

__global__ void prefix_kernel(const int* __restrict__ counts, int* __restrict__ offsets) {
    if (threadIdx.x == 0 && blockIdx.x == 0) {
        int o = 0;
        for (int e = 0; e < NEXP; e++) { offsets[e] = o; o += counts[e]; }
    }
}

// ---------------- templated 128x128 bf16 MFMA GEMM (global_load_lds staging) ----------------
// LDS layout: 1 KB blocks; block b = rblk*2 + kkb (rblk = row/16, kkb = k/32 within 64-slab).
// Within a block, chunk index = lq*16 + lm  (== consumer lane id), chunk holds
// A[rblk*16+lm][kkb*32 + lq*8 .. +7]. Producer global_load_lds writes base+lane*16;
// consumer ds_read_b128 at base+lane*16 — both lane-linear, conflict-free, no padding.
// MODE 0: routed GEMM1  (A = gathered x rows, relu, store bf16 h_buf)
// MODE 1: shared GEMM1  (A = x rows,          relu, store bf16 sh_buf)
// MODE 2: routed GEMM2  (A = h_buf rows, (acc+b)*w, atomicAdd -> Out[token])
// MODE 3: shared GEMM2  (A = sh_buf rows, acc+b,    atomicAdd -> Out[row])
template <int MODE>
__global__ __launch_bounds__(256)
void gemm_kernel(const ushort* __restrict__ A, const ushort* __restrict__ Bt,
                 const float* __restrict__ bias, ushort* __restrict__ Hout,
                 float* __restrict__ Out,
                 const int* __restrict__ counts, const int* __restrict__ offsets,
                 const int* __restrict__ expert_tok, const float* __restrict__ expert_w,
                 int K) {
    const int e = blockIdx.z;
    int cnt, rowbase = 0;
    size_t bt_off = 0;
    const float* bcol = bias;
    if constexpr (MODE == 0) {
        cnt = counts[e]; rowbase = offsets[e];
        bt_off = (size_t)e * HID * DIN; bcol = bias + (size_t)e * HID;
    } else if constexpr (MODE == 1) {
        cnt = T_TOK;
    } else if constexpr (MODE == 2) {
        cnt = counts[e]; rowbase = offsets[e];
        bt_off = (size_t)e * DOUT * HID; bcol = bias + (size_t)e * DOUT;
    } else {
        cnt = T_TOK;
    }

    const int m0 = blockIdx.y * 128;
    if (m0 >= cnt) return;
    const int n0 = blockIdx.x * 128;

    __shared__ ushort As[8192];    // 16 KB: 16 blocks x 1 KB
    __shared__ ushort Bs[8192];
    __shared__ int    rowA[128];
    __shared__ int    rowTok[128];
    __shared__ float  rowW[128];

    const int tid = threadIdx.x;
    if (tid < 128) {
        int g = m0 + tid;
        if constexpr (MODE == 0) {
            rowA[tid] = (g < cnt) ? expert_tok[e * MAXN + g] : 0;
        } else if constexpr (MODE == 1) {
            rowA[tid] = g;
        } else if constexpr (MODE == 2) {
            rowA[tid]   = (g < cnt) ? (rowbase + g) : rowbase;
            rowTok[tid] = (g < cnt) ? expert_tok[e * MAXN + g] : 0;
            rowW[tid]   = (g < cnt) ? expert_w[e * MAXN + g] : 0.f;
        } else {
            rowA[tid] = g;
        }
    }
    __syncthreads();

    const int wave = tid >> 6, lane = tid & 63;
    const int lm = lane & 15, lq = lane >> 4;

    // producer pointers: wave w stages blocks w*4 .. w*4+3 of both A and B
    const ushort* gA[4];
    const ushort* gB[4];
    ushort* dA[4];
    ushort* dB[4];
    #pragma unroll
    for (int i = 0; i < 4; i++) {
        int b = wave * 4 + i;            // 0..15
        int rblk = b >> 1, kkb = b & 1;
        int r = rblk * 16 + lm;
        gA[i] = A + (size_t)rowA[r] * K + kkb * 32 + lq * 8;
        gB[i] = Bt + bt_off + (size_t)(n0 + r) * K + kkb * 32 + lq * 8;
        dA[i] = &As[b * 512];
        dB[i] = &Bs[b * 512];
    }

    floatx4 acc[4][4];
    #pragma unroll
    for (int i = 0; i < 4; i++)
        #pragma unroll
        for (int j = 0; j < 4; j++) acc[i][j] = (floatx4){0.f, 0.f, 0.f, 0.f};

    for (int k0 = 0; k0 < K; k0 += 64) {
        #pragma unroll
        for (int i = 0; i < 4; i++) {
            load_lds_16(gA[i] + k0, dA[i]);
            load_lds_16(gB[i] + k0, dB[i]);
        }
        __syncthreads();
        #pragma unroll
        for (int kkb = 0; kkb < 2; kkb++) {
            short8 afr[4], bfr[4];
            #pragma unroll
            for (int mt = 0; mt < 4; mt++)
                afr[mt] = *(const short8*)&As[(((wave >> 1) * 4 + mt) * 2 + kkb) * 512 + lane * 8];
            #pragma unroll
            for (int nt = 0; nt < 4; nt++)
                bfr[nt] = *(const short8*)&Bs[(((wave & 1) * 4 + nt) * 2 + kkb) * 512 + lane * 8];
            #pragma unroll
            for (int mt = 0; mt < 4; mt++)
                #pragma unroll
                for (int nt = 0; nt < 4; nt++)
                    acc[mt][nt] = __builtin_amdgcn_mfma_f32_16x16x32_bf16(
                        afr[mt], bfr[nt], acc[mt][nt], 0, 0, 0);
        }
        __syncthreads();
    }

    const int wm = (wave >> 1) * 64, wn = (wave & 1) * 64;
    // epilogue: D[row = lq*4 + r][col = lane&15]
    #pragma unroll
    for (int mt = 0; mt < 4; mt++) {
        int rl_base = wm + mt * 16 + lq * 4;
        #pragma unroll
        for (int nt = 0; nt < 4; nt++) {
            int col = n0 + wn + nt * 16 + lm;
            float bv = bcol[col];
            #pragma unroll
            for (int r = 0; r < 4; r++) {
                int rl = rl_base + r;
                int g  = m0 + rl;
                float v = acc[mt][nt][r];
                if constexpr (MODE == 0) {
                    if (g < cnt) {
                        v = fmaxf(v + bv, 0.f);
                        Hout[(size_t)(rowbase + g) * HID + col] = f2bf(v);
                    }
                } else if constexpr (MODE == 1) {
                    v = fmaxf(v + bv, 0.f);
                    Hout[(size_t)g * HID + col] = f2bf(v);
                } else if constexpr (MODE == 2) {
                    if (g < cnt) {
                        v = (v + bv) * rowW[rl];
                        atomicAdd(&Out[(size_t)rowTok[rl] * DOUT + col], v);
                    }
                } else {
                    atomicAdd(&Out[(size_t)g * DOUT + col], v + bv);
                }
            }
        }
    }
}

// ---------------- launch ----------------
extern "C" void kernel_launch(void* const* d_in, const int* in_sizes, int n_in,
                              void* d_out, int out_size, void* d_ws, size_t ws_size,
                              hipStream_t stream) {
    const float* x   = (const float*)d_in[0];
    const float* gw  = (const float*)d_in[1];
    const float* gb  = (const float*)d_in[2];
    const float* ew1 = (const float*)d_in[3];
    const float* eb1 = (const float*)d_in[4];
    const float* ew2 = (const float*)d_in[5];
    const float* eb2 = (const float*)d_in[6];
    const float* sw1 = (const float*)d_in[7];
    const float* sb1 = (const float*)d_in[8];
    const float* sw2 = (const float*)d_in[9];
    const float* sb2 = (const float*)d_in[10];

    float* out_final = (float*)d_out;
    float* out_ew    = out_final + (size_t)T_TOK * DOUT;

    char* ws = (char*)d_ws;
    size_t off = 0;
    auto alloc = [&](size_t bytes) -> void* {
        void* p = ws + off;
        off += (bytes + 255) & ~(size_t)255;
        return p;
    };
    ushort* x_bf    = (ushort*)alloc((size_t)T_TOK * DIN * 2);
    ushort* ew1t    = (ushort*)alloc((size_t)NEXP * HID * DIN * 2);
    ushort* ew2t    = (ushort*)alloc((size_t)NEXP * DOUT * HID * 2);
    ushort* sw1t    = (ushort*)alloc((size_t)HID * DIN * 2);
    ushort* sw2t    = (ushort*)alloc((size_t)DOUT * HID * 2);
    ushort* h_buf   = (ushort*)alloc((size_t)T_TOK * 2 * HID * 2);   // 16384 slots
    ushort* sh_buf  = (ushort*)alloc((size_t)T_TOK * HID * 2);
    int*    counts  = (int*)alloc(NEXP * 4);
    int*    offsets = (int*)alloc(NEXP * 4);
    int*    etok    = (int*)alloc((size_t)NEXP * MAXN * 4);
    float*  ew      = (float*)alloc((size_t)NEXP * MAXN * 4);
    int*    te1     = (int*)alloc((size_t)T_TOK * 4);
    int*    te2     = (int*)alloc((size_t)T_TOK * 4);
    float*  tw1     = (float*)alloc((size_t)T_TOK * 4);
    float*  tw2     = (float*)alloc((size_t)T_TOK * 4);

    hipMemsetAsync(d_out, 0, (size_t)T_TOK * DOUT * 4, stream);   // final region only
    hipMemsetAsync(counts, 0, NEXP * 4, stream);

    convert_x_kernel<<<(T_TOK * DIN / 4) / 256, 256, 0, stream>>>(x, x_bf, T_TOK * DIN / 4);
    transpose_bf16_kernel<<<dim3(HID / 64, DIN / 64, NEXP), 256, 0, stream>>>(ew1, ew1t, DIN, HID);
    transpose_bf16_kernel<<<dim3(DOUT / 64, HID / 64, NEXP), 256, 0, stream>>>(ew2, ew2t, HID, DOUT);
    transpose_bf16_kernel<<<dim3(HID / 64, DIN / 64, 1), 256, 0, stream>>>(sw1, sw1t, DIN, HID);
    transpose_bf16_kernel<<<dim3(DOUT / 64, HID / 64, 1), 256, 0, stream>>>(sw2, sw2t, HID, DOUT);

    gate_compute_kernel<<<T_TOK / 4, 256, 0, stream>>>(x, gw, gb, out_ew, te1, te2, tw1, tw2);
    build_lists_kernel<<<T_TOK / 256, 256, 0, stream>>>(te1, te2, tw1, tw2, counts, etok, ew);
    prefix_kernel<<<1, 64, 0, stream>>>(counts, offsets);

    gemm_kernel<0><<<dim3(HID / 128, MAXN / 128, NEXP), 256, 0, stream>>>(
        x_bf, ew1t, eb1, h_buf, nullptr, counts, offsets, etok, ew, DIN);
    gemm_kernel<1><<<dim3(HID / 128, T_TOK / 128, 1), 256, 0, stream>>>(
        x_bf, sw1t, sb1, sh_buf, nullptr, counts, offsets, etok, ew, DIN);
    gemm_kernel<2><<<dim3(DOUT / 128, MAXN / 128, NEXP), 256, 0, stream>>>(
        h_buf, ew2t, eb2, nullptr, out_final, counts, offsets, etok, ew, HID);
    gemm_kernel<3><<<dim3(DOUT / 128, T_TOK / 128, 1), 256, 0, stream>>>(
        sh_buf, sw2t, sb2, nullptr, out_final, counts, offsets, etok, ew, HID);
}